// Round 6
// baseline (791.678 us; speedup 1.0000x reference)
//
#include <hip/hip_runtime.h>
#include <cstddef>

#define B_ 64
#define T_ 256
#define C_ 2048
#define H_ 512
#define O_ 11
#define THRESH 1.0f
#define LEAK_ 0.003f
#define OLEAK_ 0.0015f

// Raw workgroup barrier: orders LDS ops (lgkmcnt) but does NOT drain vmcnt,
// so prefetched global loads stay in flight across the barrier.
__device__ __forceinline__ void lds_barrier() {
    asm volatile("s_waitcnt lgkmcnt(0)" ::: "memory");
    __builtin_amdgcn_s_barrier();
}

// ---------------------------------------------------------------------------
// Kernel 1: transpose w_rec (H x H) -> w_recT (coalesced recurrent gather).
// ---------------------------------------------------------------------------
__global__ __launch_bounds__(256) void transpose_wrec(const float* __restrict__ w,
                                                      float* __restrict__ wt) {
    __shared__ float tile[32][33];
    int tx = threadIdx.x, ty = threadIdx.y;           // block (32, 8)
    int x = blockIdx.x * 32 + tx;
    int y = blockIdx.y * 32 + ty;
#pragma unroll
    for (int i = 0; i < 32; i += 8)
        tile[ty + i][tx] = w[(size_t)(y + i) * H_ + x];
    __syncthreads();
    int x2 = blockIdx.y * 32 + tx;
    int y2 = blockIdx.x * 32 + ty;
#pragma unroll
    for (int i = 0; i < 32; i += 8)
        wt[(size_t)(y2 + i) * H_ + x2] = tile[tx][ty + i];
}

// ---------------------------------------------------------------------------
// Kernel 2: feedforward GEMM  P[s] = X @ w1^T  over K-chunk s (split-K).
// 256 threads, 128x128 tile, BK=16, 8x8 microtile, LDS double-buffer with
// one lgkmcnt-only barrier per K-tile, +4 skew, XCD-chunked swizzle.
// THIS ROUND: scalar v_fma_f32 accumulation (v_pk_fma_f32 measured 4cy =
// no rate gain, and its {x,x} broadcasts cost 8 v_movs per k-step).
// Per-element K-chain order identical to all passing rounds (bit-exact).
// ---------------------------------------------------------------------------
#define BM 128
#define BN 128
#define BK 16
#define LDT (BM + 4)

template <int S>
__global__ __launch_bounds__(256) void gemm_ff(const float* __restrict__ A,
                                               const float* __restrict__ Bw,
                                               float* __restrict__ Pout) {
    const int K = C_;
    const int N = H_;
    const int kLen = C_ / S;

    // XCD-chunked swizzle (grid = 4*128*S = 512*S blocks, % 8 == 0 always)
    const int i  = blockIdx.x + 4 * blockIdx.y + 512 * blockIdx.z;
    const int l  = (i & 7) * (64 * S) + (i >> 3);
    const int bx = l & 3;
    const int by = (l >> 2) & 127;
    const int bz = l >> 9;
    const int kBase = bz * kLen;

    __shared__ float As[2][BK][LDT];
    __shared__ float Bs[2][BK][LDT];

    const int t  = threadIdx.x;
    const int tx = t & 15;        // n-dir
    const int ty = t >> 4;        // m-dir
    const int lr = t >> 2;        // load row 0..63
    const int lc = (t & 3) * 4;   // load col 0,4,8,12

    const float* Ap = A  + (size_t)(by * BM + lr) * K + kBase + lc;
    const float* Bp = Bw + (size_t)(bx * BN + lr) * K + kBase + lc;

    float acc[8][8];
#pragma unroll
    for (int ii = 0; ii < 8; ++ii)
#pragma unroll
        for (int jj = 0; jj < 8; ++jj) acc[ii][jj] = 0.f;

    float4 a0 = *(const float4*)(Ap);
    float4 a1 = *(const float4*)(Ap + (size_t)64 * K);
    float4 b0 = *(const float4*)(Bp);
    float4 b1 = *(const float4*)(Bp + (size_t)64 * K);

    auto stage = [&](int pb) {
        As[pb][lc + 0][lr] = a0.x; As[pb][lc + 1][lr] = a0.y;
        As[pb][lc + 2][lr] = a0.z; As[pb][lc + 3][lr] = a0.w;
        As[pb][lc + 0][lr + 64] = a1.x; As[pb][lc + 1][lr + 64] = a1.y;
        As[pb][lc + 2][lr + 64] = a1.z; As[pb][lc + 3][lr + 64] = a1.w;
        Bs[pb][lc + 0][lr] = b0.x; Bs[pb][lc + 1][lr] = b0.y;
        Bs[pb][lc + 2][lr] = b0.z; Bs[pb][lc + 3][lr] = b0.w;
        Bs[pb][lc + 0][lr + 64] = b1.x; Bs[pb][lc + 1][lr + 64] = b1.y;
        Bs[pb][lc + 2][lr + 64] = b1.z; Bs[pb][lc + 3][lr + 64] = b1.w;
    };

    auto compute = [&](int pb) {
#pragma unroll
        for (int k = 0; k < BK; ++k) {
            float4 alo = *(const float4*)&As[pb][k][ty * 4];
            float4 ahi = *(const float4*)&As[pb][k][64 + ty * 4];
            float4 blo = *(const float4*)&Bs[pb][k][tx * 4];
            float4 bhi = *(const float4*)&Bs[pb][k][64 + tx * 4];
            float av[8] = {alo.x, alo.y, alo.z, alo.w, ahi.x, ahi.y, ahi.z, ahi.w};
            float bv[8] = {blo.x, blo.y, blo.z, blo.w, bhi.x, bhi.y, bhi.z, bhi.w};
#pragma unroll
            for (int ii = 0; ii < 8; ++ii)
#pragma unroll
                for (int jj = 0; jj < 8; ++jj)
                    acc[ii][jj] = __builtin_fmaf(av[ii], bv[jj], acc[ii][jj]);
        }
    };

    stage(0);
    __syncthreads();

    int p = 0;
    for (int k0 = BK; k0 < kLen; k0 += BK) {
        Ap += BK; Bp += BK;
        a0 = *(const float4*)(Ap);
        a1 = *(const float4*)(Ap + (size_t)64 * K);
        b0 = *(const float4*)(Bp);
        b1 = *(const float4*)(Bp + (size_t)64 * K);
        compute(p);           // FMAs on current buffer hide the global latency
        stage(p ^ 1);         // vmcnt wait folded here, after ~2700 cy of FMA
        lds_barrier();        // ONE barrier per K-tile
        p ^= 1;
    }
    compute(p);

    float* P = Pout + (size_t)bz * ((size_t)B_ * T_ * H_);
#pragma unroll
    for (int ii = 0; ii < 8; ++ii) {
        int row = by * BM + (ii < 4 ? ty * 4 + ii : 64 + ty * 4 + (ii - 4));
        float* Cp = P + (size_t)row * N + bx * BN;
        float4 c0 = {acc[ii][0], acc[ii][1], acc[ii][2], acc[ii][3]};
        float4 c1 = {acc[ii][4], acc[ii][5], acc[ii][6], acc[ii][7]};
        *(float4*)(Cp + tx * 4)      = c0;   // plain: keep P L2/L3-resident
        *(float4*)(Cp + 64 + tx * 4) = c1;
    }
}

// ---------------------------------------------------------------------------
// Kernel 3: recurrent LIF scan.  Compacted-list structure, lgkmcnt-only
// barriers (round 5, proven).  THIS ROUND:
//   * output pass batched 8-wide: the rolled  s2 += w2sT[cl[j]*12+h]  loop
//     was a ~120cy-per-element dependent LDS chain (~1200 cy/step on the
//     wave-0 critical path); batching issues 8 independent loads per wait,
//     adds remain in ascending-j order (bit-exact)
//   * v2 / osum moved from LDS to registers (lanes h < O_ own them)
// ---------------------------------------------------------------------------
template <int S>
__global__ __launch_bounds__(512) void snn_rec(const float* __restrict__ I1,
                                               const float* __restrict__ wrT,
                                               const float* __restrict__ w2,
                                               float* __restrict__ out) {
    const int b    = blockIdx.x;
    const int h    = threadIdx.x;
    const int lane = h & 63;
    const int w    = h >> 6;

    __shared__ float w2sT[H_ * 12];       // [k][o] stride 12 (conflict-free)
    __shared__ int   lists[2][H_];
    __shared__ int   wcnt[8];

#pragma unroll
    for (int o = 0; o < O_; ++o) w2sT[h * 12 + o] = w2[o * H_ + h];

    float v1 = 0.f;
    float v2 = 0.f;      // live only in h < O_
    float osum = 0.f;    // live only in h < O_
    int   pc = 0;
    const float*  i1p  = I1 + (size_t)b * T_ * H_ + h;
    const float*  wr_h = wrT + h;
    const size_t  PARTF = (size_t)B_ * T_ * H_;

    float pf[S];
#pragma unroll
    for (int s = 0; s < S; ++s) pf[s] = i1p[s * PARTF];   // t=0 prefetch
    __syncthreads();

    for (int t = 0; t < T_; ++t) {
        const int cur = t & 1;

        float acc = -LEAK_;
#pragma unroll
        for (int s = 0; s < S; ++s) acc += pf[s];

        // prefetch next step's feedforward current (stays in flight across
        // the raw barriers below -> latency fully hidden)
        const int tn = (t + 1 < T_) ? t + 1 : t;
#pragma unroll
        for (int s = 0; s < S; ++s) pf[s] = i1p[s * PARTF + (size_t)tn * H_];

        // recurrent gather: 16 loads in flight, ascending-index add order
        const int* pl = lists[cur ^ 1];
        int j = 0;
        for (; j + 15 < pc; j += 16) {
            const int4 ia = *(const int4*)(pl + j);
            const int4 ib = *(const int4*)(pl + j + 4);
            const int4 ic = *(const int4*)(pl + j + 8);
            const int4 id = *(const int4*)(pl + j + 12);
            float g0 = wr_h[ia.x * H_], g1 = wr_h[ia.y * H_];
            float g2 = wr_h[ia.z * H_], g3 = wr_h[ia.w * H_];
            float g4 = wr_h[ib.x * H_], g5 = wr_h[ib.y * H_];
            float g6 = wr_h[ib.z * H_], g7 = wr_h[ib.w * H_];
            float g8 = wr_h[ic.x * H_], g9 = wr_h[ic.y * H_];
            float gA = wr_h[ic.z * H_], gB = wr_h[ic.w * H_];
            float gC = wr_h[id.x * H_], gD = wr_h[id.y * H_];
            float gE = wr_h[id.z * H_], gF = wr_h[id.w * H_];
            acc += g0; acc += g1; acc += g2; acc += g3;
            acc += g4; acc += g5; acc += g6; acc += g7;
            acc += g8; acc += g9; acc += gA; acc += gB;
            acc += gC; acc += gD; acc += gE; acc += gF;
        }
        for (; j + 7 < pc; j += 8) {
            const int4 ia = *(const int4*)(pl + j);
            const int4 ib = *(const int4*)(pl + j + 4);
            float g0 = wr_h[ia.x * H_], g1 = wr_h[ia.y * H_];
            float g2 = wr_h[ia.z * H_], g3 = wr_h[ia.w * H_];
            float g4 = wr_h[ib.x * H_], g5 = wr_h[ib.y * H_];
            float g6 = wr_h[ib.z * H_], g7 = wr_h[ib.w * H_];
            acc += g0; acc += g1; acc += g2; acc += g3;
            acc += g4; acc += g5; acc += g6; acc += g7;
        }
        for (; j < pc; ++j) acc += wr_h[pl[j] * H_];

        // LIF update, subtractive reset
        v1 += acc;
        const bool spike = (v1 >= THRESH);
        if (spike) v1 -= THRESH;

        // ballot compaction
        unsigned long long m = __ballot(spike);
        int lb = __popcll(m & ((1ull << lane) - 1ull));
        if (lane == 0) wcnt[w] = (int)__popcll(m);
        lds_barrier();                      // B1: wcnt ready (no vmcnt drain)

        int base = 0, tot = 0;
#pragma unroll
        for (int ww = 0; ww < 8; ++ww) {
            int c = wcnt[ww];
            if (ww < w) base += c;
            tot += c;
        }
        if (spike) lists[cur][base + lb] = h;
        lds_barrier();                      // B2: list complete (no vmcnt drain)

        // output neuron update (11 threads; other waves run ahead to gather).
        // 8-wide batched loads, adds in ascending-j order (bit-exact).
        if (h < O_) {
            const int* cl = lists[cur];
            float s2 = 0.f;
            int j2 = 0;
            for (; j2 + 7 < tot; j2 += 8) {
                int i0 = cl[j2 + 0], i1 = cl[j2 + 1], i2 = cl[j2 + 2], i3 = cl[j2 + 3];
                int i4 = cl[j2 + 4], i5 = cl[j2 + 5], i6 = cl[j2 + 6], i7 = cl[j2 + 7];
                float g0 = w2sT[i0 * 12 + h], g1 = w2sT[i1 * 12 + h];
                float g2 = w2sT[i2 * 12 + h], g3 = w2sT[i3 * 12 + h];
                float g4 = w2sT[i4 * 12 + h], g5 = w2sT[i5 * 12 + h];
                float g6 = w2sT[i6 * 12 + h], g7 = w2sT[i7 * 12 + h];
                s2 += g0; s2 += g1; s2 += g2; s2 += g3;
                s2 += g4; s2 += g5; s2 += g6; s2 += g7;
            }
            for (; j2 < tot; ++j2) s2 += w2sT[cl[j2] * 12 + h];
            float nv2 = v2 + s2 - OLEAK_;
            v2 = nv2 > 0.f ? nv2 : 0.f;
            osum += v2;
        }
        pc = tot;
    }
    if (h < O_) out[b * O_ + h] = osum * (1.0f / (float)T_);
}

// ---------------------------------------------------------------------------
extern "C" void kernel_launch(void* const* d_in, const int* in_sizes, int n_in,
                              void* d_out, int out_size, void* d_ws, size_t ws_size,
                              hipStream_t stream) {
    const float* x     = (const float*)d_in[0];   // (B,T,C)
    const float* w1    = (const float*)d_in[1];   // (H,C)
    const float* w_rec = (const float*)d_in[2];   // (H,H)
    const float* w2    = (const float*)d_in[3];   // (O,H)
    float* out = (float*)d_out;                   // (B,O)

    const size_t PART = (size_t)B_ * T_ * H_ * sizeof(float);   // 32 MB
    const size_t WRT  = (size_t)H_ * H_ * sizeof(float);        // 1 MB

    int S = 1;
    if (ws_size >= 4 * PART + WRT) S = 4;
    else if (ws_size >= 2 * PART + WRT) S = 2;

    float* P   = (float*)d_ws;
    float* wrT = (float*)((char*)d_ws + (size_t)S * PART);

    transpose_wrec<<<dim3(H_ / 32, H_ / 32), dim3(32, 8), 0, stream>>>(w_rec, wrT);

    dim3 ggrid(H_ / BN, (B_ * T_) / BM, S);
    switch (S) {
        case 4:
            gemm_ff<4><<<ggrid, dim3(256), 0, stream>>>(x, w1, P);
            snn_rec<4><<<dim3(B_), dim3(H_), 0, stream>>>(P, wrT, w2, out);
            break;
        case 2:
            gemm_ff<2><<<ggrid, dim3(256), 0, stream>>>(x, w1, P);
            snn_rec<2><<<dim3(B_), dim3(H_), 0, stream>>>(P, wrT, w2, out);
            break;
        default:
            gemm_ff<1><<<ggrid, dim3(256), 0, stream>>>(x, w1, P);
            snn_rec<1><<<dim3(B_), dim3(H_), 0, stream>>>(P, wrT, w2, out);
            break;
    }
}

// Round 7
// 741.068 us; speedup vs baseline: 1.0683x; 1.0683x over previous
//
#include <hip/hip_runtime.h>
#include <cstddef>

#define B_ 64
#define T_ 256
#define C_ 2048
#define H_ 512
#define O_ 11
#define THRESH 1.0f
#define LEAK_ 0.003f
#define OLEAK_ 0.0015f

typedef float v2f __attribute__((ext_vector_type(2)));

// Raw workgroup barrier: orders LDS ops (lgkmcnt) but does NOT drain vmcnt,
// so prefetched global loads stay in flight across the barrier.
__device__ __forceinline__ void lds_barrier() {
    asm volatile("s_waitcnt lgkmcnt(0)" ::: "memory");
    __builtin_amdgcn_s_barrier();
}

// ---------------------------------------------------------------------------
// Kernel 1: transpose w_rec (H x H) -> w_recT (coalesced recurrent gather).
// ---------------------------------------------------------------------------
__global__ __launch_bounds__(256) void transpose_wrec(const float* __restrict__ w,
                                                      float* __restrict__ wt) {
    __shared__ float tile[32][33];
    int tx = threadIdx.x, ty = threadIdx.y;           // block (32, 8)
    int x = blockIdx.x * 32 + tx;
    int y = blockIdx.y * 32 + ty;
#pragma unroll
    for (int i = 0; i < 32; i += 8)
        tile[ty + i][tx] = w[(size_t)(y + i) * H_ + x];
    __syncthreads();
    int x2 = blockIdx.y * 32 + tx;
    int y2 = blockIdx.x * 32 + ty;
#pragma unroll
    for (int i = 0; i < 32; i += 8)
        wt[(size_t)(y2 + i) * H_ + x2] = tile[tx][ty + i];
}

// ---------------------------------------------------------------------------
// Kernel 2: feedforward GEMM  P[s] = X @ w1^T  over K-chunk s (split-K).
// ROUND-5 EXACT REVERT (measured 382 us, VGPR 72): 256 threads, 128x128
// tile, BK=16, 8x8 v2f microtile (v_pk_fma_f32 = 4cy = same FLOP rate as
// 2x scalar v_fma, but half the acc registers -> occupancy), LDS double-
// buffer with one lgkmcnt-only barrier per K-tile, +4 skew, XCD-chunked
// swizzle, plain C stores (P stays L2/L3-resident for snn_rec).
// ---------------------------------------------------------------------------
#define BM 128
#define BN 128
#define BK 16
#define LDT (BM + 4)

template <int S>
__global__ __launch_bounds__(256) void gemm_ff(const float* __restrict__ A,
                                               const float* __restrict__ Bw,
                                               float* __restrict__ Pout) {
    const int K = C_;
    const int N = H_;
    const int kLen = C_ / S;

    // XCD-chunked swizzle (grid = 4*128*S = 512*S blocks, % 8 == 0 always)
    const int i  = blockIdx.x + 4 * blockIdx.y + 512 * blockIdx.z;
    const int l  = (i & 7) * (64 * S) + (i >> 3);
    const int bx = l & 3;
    const int by = (l >> 2) & 127;
    const int bz = l >> 9;
    const int kBase = bz * kLen;

    __shared__ float As[2][BK][LDT];
    __shared__ float Bs[2][BK][LDT];

    const int t  = threadIdx.x;
    const int tx = t & 15;        // n-dir
    const int ty = t >> 4;        // m-dir
    const int lr = t >> 2;        // load row 0..63
    const int lc = (t & 3) * 4;   // load col 0,4,8,12

    const float* Ap = A  + (size_t)(by * BM + lr) * K + kBase + lc;
    const float* Bp = Bw + (size_t)(bx * BN + lr) * K + kBase + lc;

    v2f acc[8][4];
#pragma unroll
    for (int ii = 0; ii < 8; ++ii)
#pragma unroll
        for (int j = 0; j < 4; ++j) acc[ii][j] = (v2f){0.f, 0.f};

    float4 a0 = *(const float4*)(Ap);
    float4 a1 = *(const float4*)(Ap + (size_t)64 * K);
    float4 b0 = *(const float4*)(Bp);
    float4 b1 = *(const float4*)(Bp + (size_t)64 * K);

    auto stage = [&](int pb) {
        As[pb][lc + 0][lr] = a0.x; As[pb][lc + 1][lr] = a0.y;
        As[pb][lc + 2][lr] = a0.z; As[pb][lc + 3][lr] = a0.w;
        As[pb][lc + 0][lr + 64] = a1.x; As[pb][lc + 1][lr + 64] = a1.y;
        As[pb][lc + 2][lr + 64] = a1.z; As[pb][lc + 3][lr + 64] = a1.w;
        Bs[pb][lc + 0][lr] = b0.x; Bs[pb][lc + 1][lr] = b0.y;
        Bs[pb][lc + 2][lr] = b0.z; Bs[pb][lc + 3][lr] = b0.w;
        Bs[pb][lc + 0][lr + 64] = b1.x; Bs[pb][lc + 1][lr + 64] = b1.y;
        Bs[pb][lc + 2][lr + 64] = b1.z; Bs[pb][lc + 3][lr + 64] = b1.w;
    };

    auto compute = [&](int pb) {
#pragma unroll
        for (int k = 0; k < BK; ++k) {
            float4 alo = *(const float4*)&As[pb][k][ty * 4];
            float4 ahi = *(const float4*)&As[pb][k][64 + ty * 4];
            float4 blo = *(const float4*)&Bs[pb][k][tx * 4];
            float4 bhi = *(const float4*)&Bs[pb][k][64 + tx * 4];
            v2f b0v = {blo.x, blo.y}, b1v = {blo.z, blo.w};
            v2f b2v = {bhi.x, bhi.y}, b3v = {bhi.z, bhi.w};
            float av[8] = {alo.x, alo.y, alo.z, alo.w, ahi.x, ahi.y, ahi.z, ahi.w};
#pragma unroll
            for (int ii = 0; ii < 8; ++ii) {
                v2f ai = {av[ii], av[ii]};
                acc[ii][0] += ai * b0v;
                acc[ii][1] += ai * b1v;
                acc[ii][2] += ai * b2v;
                acc[ii][3] += ai * b3v;
            }
        }
    };

    stage(0);
    __syncthreads();

    int p = 0;
    for (int k0 = BK; k0 < kLen; k0 += BK) {
        Ap += BK; Bp += BK;
        a0 = *(const float4*)(Ap);
        a1 = *(const float4*)(Ap + (size_t)64 * K);
        b0 = *(const float4*)(Bp);
        b1 = *(const float4*)(Bp + (size_t)64 * K);
        compute(p);           // FMAs on current buffer hide the global latency
        stage(p ^ 1);         // vmcnt wait folded here, after ~2700 cy of FMA
        lds_barrier();        // ONE barrier per K-tile
        p ^= 1;
    }
    compute(p);

    float* P = Pout + (size_t)bz * ((size_t)B_ * T_ * H_);
#pragma unroll
    for (int ii = 0; ii < 8; ++ii) {
        int row = by * BM + (ii < 4 ? ty * 4 + ii : 64 + ty * 4 + (ii - 4));
        float* Cp = P + (size_t)row * N + bx * BN;
        float4 c0 = {acc[ii][0].x, acc[ii][0].y, acc[ii][1].x, acc[ii][1].y};
        float4 c1 = {acc[ii][2].x, acc[ii][2].y, acc[ii][3].x, acc[ii][3].y};
        *(float4*)(Cp + tx * 4)      = c0;   // plain: keep P L2/L3-resident
        *(float4*)(Cp + 64 + tx * 4) = c1;
    }
}

// ---------------------------------------------------------------------------
// Kernel 3: recurrent LIF scan — ONE WAVE per batch, 8 neurons per lane.
// __ballot per neuron-row gives the complete wave-uniform spike mask:
// NO LDS lists, NO prefix machinery, ZERO in-loop barriers.  Gather and
// output walk the 8 uniform masks with ctz (register-serial extraction,
// loads pipeline); per-neuron add order = ascending source index, output
// sums ascending, v2/osum chains unchanged -> bit-exact vs round 6.
// Spike rate is ~2-5/step (random-walk drive), so gather is tiny and the
// old 2-barrier/8-wave structure was pure overhead (~2690 cy/step).
// ---------------------------------------------------------------------------
template <int S>
__global__ __launch_bounds__(64) void snn_rec(const float* __restrict__ I1,
                                              const float* __restrict__ wrT,
                                              const float* __restrict__ w2,
                                              float* __restrict__ out) {
    const int b = blockIdx.x;
    const int l = threadIdx.x;            // lane 0..63; neuron = l + 64*r
    const size_t PARTF = (size_t)B_ * T_ * H_;

    __shared__ float w2sT[H_ * 12];       // [k][o] stride 12
    for (int k = l; k < H_; k += 64)
#pragma unroll
        for (int o = 0; o < O_; ++o) w2sT[k * 12 + o] = w2[o * H_ + k];
    __syncthreads();                      // once; LDS ready

    float v1[8];
#pragma unroll
    for (int r = 0; r < 8; ++r) v1[r] = 0.f;
    float v2 = 0.f, osum = 0.f;           // live in lanes < O_
    unsigned long long pmask[8];
#pragma unroll
    for (int r = 0; r < 8; ++r) pmask[r] = 0ull;

    const unsigned off0 = (unsigned)(b * T_ * H_) + (unsigned)l;  // float idx

    float pf[S][8];
#pragma unroll
    for (int s = 0; s < S; ++s)
#pragma unroll
        for (int r = 0; r < 8; ++r)
            pf[s][r] = I1[(size_t)s * PARTF + off0 + r * 64];     // t = 0

    for (int t = 0; t < T_; ++t) {
        // feedforward current (s-major add order, identical to prior rounds)
        float acc[8];
#pragma unroll
        for (int r = 0; r < 8; ++r) {
            acc[r] = -LEAK_;
#pragma unroll
            for (int s = 0; s < S; ++s) acc[r] += pf[s][r];
        }

        // issue next step's prefetch NOW: latency hides under gather+output
        const unsigned offn = off0 + (unsigned)(((t + 1 < T_) ? t + 1 : t) * H_);
#pragma unroll
        for (int s = 0; s < S; ++s)
#pragma unroll
            for (int r = 0; r < 8; ++r)
                pf[s][r] = I1[(size_t)s * PARTF + offn + r * 64];

        // recurrent gather: walk prev-step masks (wave-uniform), ascending
        // source idx; 8 coalesced loads per spike (one row of wrT)
#pragma unroll
        for (int w = 0; w < 8; ++w) {
            unsigned long long m = pmask[w];
            while (m) {
                const int idx = (w << 6) + (int)__builtin_ctzll(m);
                m &= m - 1;
                const float* row = wrT + (size_t)idx * H_ + l;
                float g0 = row[0 * 64], g1 = row[1 * 64];
                float g2 = row[2 * 64], g3 = row[3 * 64];
                float g4 = row[4 * 64], g5 = row[5 * 64];
                float g6 = row[6 * 64], g7 = row[7 * 64];
                acc[0] += g0; acc[1] += g1; acc[2] += g2; acc[3] += g3;
                acc[4] += g4; acc[5] += g5; acc[6] += g6; acc[7] += g7;
            }
        }

        // LIF update + ballot per neuron-row (pmask consumed above, safe)
#pragma unroll
        for (int r = 0; r < 8; ++r) {
            v1[r] += acc[r];
            const bool sp = (v1[r] >= THRESH);
            if (sp) v1[r] -= THRESH;
            pmask[r] = __ballot(sp);
        }

        // output neurons (lanes < O_): ascending idx sum, same chain as ever
        if (l < O_) {
            float s2 = 0.f;
#pragma unroll
            for (int w = 0; w < 8; ++w) {
                unsigned long long m = pmask[w];
                while (m) {
                    const int idx = (w << 6) + (int)__builtin_ctzll(m);
                    m &= m - 1;
                    s2 += w2sT[idx * 12 + l];
                }
            }
            float nv2 = v2 + s2 - OLEAK_;
            v2 = nv2 > 0.f ? nv2 : 0.f;
            osum += v2;
        }
    }
    if (l < O_) out[b * O_ + l] = osum * (1.0f / (float)T_);
}

// ---------------------------------------------------------------------------
extern "C" void kernel_launch(void* const* d_in, const int* in_sizes, int n_in,
                              void* d_out, int out_size, void* d_ws, size_t ws_size,
                              hipStream_t stream) {
    const float* x     = (const float*)d_in[0];   // (B,T,C)
    const float* w1    = (const float*)d_in[1];   // (H,C)
    const float* w_rec = (const float*)d_in[2];   // (H,H)
    const float* w2    = (const float*)d_in[3];   // (O,H)
    float* out = (float*)d_out;                   // (B,O)

    const size_t PART = (size_t)B_ * T_ * H_ * sizeof(float);   // 32 MB
    const size_t WRT  = (size_t)H_ * H_ * sizeof(float);        // 1 MB

    int S = 1;
    if (ws_size >= 4 * PART + WRT) S = 4;
    else if (ws_size >= 2 * PART + WRT) S = 2;

    float* P   = (float*)d_ws;
    float* wrT = (float*)((char*)d_ws + (size_t)S * PART);

    transpose_wrec<<<dim3(H_ / 32, H_ / 32), dim3(32, 8), 0, stream>>>(w_rec, wrT);

    dim3 ggrid(H_ / BN, (B_ * T_) / BM, S);
    switch (S) {
        case 4:
            gemm_ff<4><<<ggrid, dim3(256), 0, stream>>>(x, w1, P);
            snn_rec<4><<<dim3(B_), dim3(64), 0, stream>>>(P, wrT, w2, out);
            break;
        case 2:
            gemm_ff<2><<<ggrid, dim3(256), 0, stream>>>(x, w1, P);
            snn_rec<2><<<dim3(B_), dim3(64), 0, stream>>>(P, wrT, w2, out);
            break;
        default:
            gemm_ff<1><<<ggrid, dim3(256), 0, stream>>>(x, w1, P);
            snn_rec<1><<<dim3(B_), dim3(64), 0, stream>>>(P, wrT, w2, out);
            break;
    }
}